// Round 1
// 885.554 us; speedup vs baseline: 1.0388x; 1.0388x over previous
//
#include <hip/hip_runtime.h>

// CurvGN 2-layer graph net, N=100k nodes, E=3.2M edges, 256->64->16.
// Algebra: edge-MLP logits = w_mul[e] * (w>0 ? gpos[i] : gneg[i]) + b2[i];
// b2 cancels in per-src segment softmax. Segment max from per-src w endpoints.
// out[d][i] = sum_e exp(w_e*g_i) * q[src][i],  q = x*exp(-m)/(den+1e-16).
//
// CSR build REWRITE (this round): prior rounds proved device-scope atomics cap
// at ~19-21 G/s (6.4M atomics = 305+ us floor; WRITE_SIZE showed ~32B/atomic
// write-through past L2). Replaced with a 2-level bucketed counting sort whose
// rank atomics are ALL LDS-scope:
//   P1 fused_hist_gemm1_k : per-block LDS bucket histograms (bucket=node>>7)
//                           for src+dst; every 5th block runs a gemm1 tile.
//   P2a scanblk_k         : per-bucket exclusive prefix over blocks (in place).
//   P2b bukscan_k         : exclusive scan of bucket totals -> bucket bases.
//   P3 bucket_scatter_k   : pos = base[bucket] + blockprefix + LDS-atomic rank;
//                           writes bucket-major (key,w) temps. dst payload
//                           packs s | (d&127)<<17 (s < 2^17).
//   P4 bucket_rank_k      : one block per (sort,bucket): LDS 128-bin count ->
//                           block scan -> offS/offD; cursor pass emits csw/csde.
// Downstream kernels unchanged; csw/csde/offS/offD formats identical.

#define CHUNK 4096
#define MAXBUK 1024   // supports N <= 131072 (N=100k -> NBUK=782)

static __device__ __forceinline__ int ld_idx(const void* ei, long long pos, int is64) {
  return is64 ? (int)((const long long*)ei)[pos] : ((const int*)ei)[pos];
}

static __device__ __forceinline__ int detect64(const void* ei, int E) {
  // int64 little-endian: high words of small nonneg values are 0
  const unsigned* u = (const unsigned*)ei;
  unsigned o = 0;
  int lim = (2 * E < 32) ? 2 * E : 32;
  for (int t = 1; t < lim; t += 2) o |= u[t];
  return o == 0u;
}

// ---- K1: collapse edge MLPs: g[0:64]=gpos1 g[64:128]=gneg1 g[128:144]=gpos2 g[144:160]=gneg2
__global__ void gvec_k(const float* __restrict__ w1a, const float* __restrict__ w2a,
                       const float* __restrict__ w1b, const float* __restrict__ w2b,
                       float* __restrict__ g) {
  int i = threadIdx.x;
  if (i < 64) {
    float sp = 0.f, sn = 0.f;
    for (int j = 0; j < 64; ++j) {
      float a = w1a[j], b = w2a[i * 64 + j], ab = a * b;
      sp += ab * (a > 0.f ? 1.f : 0.2f);
      sn += ab * (a < 0.f ? 1.f : 0.2f);
    }
    g[i] = sp; g[64 + i] = sn;
  }
  if (i < 16) {
    float sp = 0.f, sn = 0.f;
    for (int j = 0; j < 16; ++j) {
      float a = w1b[j], b = w2b[i * 16 + j], ab = a * b;
      sp += ab * (a > 0.f ? 1.f : 0.2f);
      sn += ab * (a < 0.f ? 1.f : 0.2f);
    }
    g[128 + i] = sp; g[144 + i] = sn;
  }
}

// ---- P1 (fused): block role by blockIdx: r==4 -> gemm1 tile, else bucket hist.
__global__ __launch_bounds__(256) void fused_hist_gemm1_k(
    const void* __restrict__ ei, int* __restrict__ bhS, int* __restrict__ bhD,
    int E, int EB, int NBUK, int NB,
    const float* __restrict__ x, const float* __restrict__ W,
    const float* __restrict__ b, float* __restrict__ x1, int N, int GB) {
  __shared__ __align__(16) float Al[128 * 36];
  __shared__ __align__(16) float Bl[64 * 36];
  int k = blockIdx.x, q = k / 5, r = k - q * 5;
  if (r == 4) {
    // ---------------- gemm1 tile: x1 = x @ lin1_w.T + b, 128x64 per block ----
    int gid = q;
    if (gid >= GB) return;
    int t = threadIdx.x;
    int n0 = gid * 128;
    int tm = t & 31, tc = t >> 5;
    int lr = t >> 3, lc = (t & 7) * 4;
    float acc[4][8];
    #pragma unroll
    for (int j = 0; j < 4; ++j)
      #pragma unroll
      for (int jj = 0; jj < 8; ++jj) acc[j][jj] = 0.f;
    for (int k0 = 0; k0 < 256; k0 += 32) {
      #pragma unroll
      for (int l = 0; l < 4; ++l) {
        int row = lr + l * 32;
        int n = n0 + row;
        float4 v = (n < N) ? *(const float4*)&x[(size_t)n * 256 + k0 + lc]
                           : make_float4(0.f, 0.f, 0.f, 0.f);
        *(float4*)&Al[row * 36 + lc] = v;
      }
      #pragma unroll
      for (int l = 0; l < 2; ++l) {
        int row = lr + l * 32;
        *(float4*)&Bl[row * 36 + lc] = *(const float4*)&W[row * 256 + k0 + lc];
      }
      __syncthreads();
      #pragma unroll
      for (int k4 = 0; k4 < 8; ++k4) {
        float4 a0 = *(const float4*)&Al[tm * 36 + k4 * 4];
        float4 a1 = *(const float4*)&Al[(tm + 32) * 36 + k4 * 4];
        float4 a2 = *(const float4*)&Al[(tm + 64) * 36 + k4 * 4];
        float4 a3 = *(const float4*)&Al[(tm + 96) * 36 + k4 * 4];
        #pragma unroll
        for (int jj = 0; jj < 8; ++jj) {
          float4 bv = *(const float4*)&Bl[(tc * 8 + jj) * 36 + k4 * 4];
          acc[0][jj] += a0.x * bv.x + a0.y * bv.y + a0.z * bv.z + a0.w * bv.w;
          acc[1][jj] += a1.x * bv.x + a1.y * bv.y + a1.z * bv.z + a1.w * bv.w;
          acc[2][jj] += a2.x * bv.x + a2.y * bv.y + a2.z * bv.z + a2.w * bv.w;
          acc[3][jj] += a3.x * bv.x + a3.y * bv.y + a3.z * bv.z + a3.w * bv.w;
        }
      }
      __syncthreads();
    }
    float bb[8];
    #pragma unroll
    for (int jj = 0; jj < 8; ++jj) bb[jj] = b[tc * 8 + jj];
    #pragma unroll
    for (int j = 0; j < 4; ++j) {
      int n = n0 + tm + j * 32;
      if (n < N) {
        float4 o0 = make_float4(acc[j][0] + bb[0], acc[j][1] + bb[1], acc[j][2] + bb[2], acc[j][3] + bb[3]);
        float4 o1 = make_float4(acc[j][4] + bb[4], acc[j][5] + bb[5], acc[j][6] + bb[6], acc[j][7] + bb[7]);
        *(float4*)&x1[(size_t)n * 64 + tc * 8] = o0;
        *(float4*)&x1[(size_t)n * 64 + tc * 8 + 4] = o1;
      }
    }
  } else {
    // ---------------- bucket histogram (LDS atomics only) ----------------
    int eid = k - q;           // bijective over blocks with r<4
    if (eid >= EB) return;
    int* cS = (int*)Al;        // reuse gemm LDS: 2*MAXBUK ints = 8KB <= Al
    int* cD = ((int*)Al) + MAXBUK;
    __shared__ int s64;
    if (threadIdx.x == 0) s64 = detect64(ei, E);
    for (int i = threadIdx.x; i < NBUK; i += 256) { cS[i] = 0; cD[i] = 0; }
    __syncthreads();
    int is64 = s64;
    int base = eid * CHUNK + threadIdx.x;
    #pragma unroll
    for (int kk = 0; kk < CHUNK / 256; ++kk) {
      int e = base + kk * 256;
      if (e < E) {
        int s = ld_idx(ei, e, is64);
        int d = ld_idx(ei, (long long)e + E, is64);
        atomicAdd(&cS[s >> 7], 1);
        atomicAdd(&cD[d >> 7], 1);
      }
    }
    __syncthreads();
    for (int i = threadIdx.x; i < NBUK; i += 256) {
      bhS[i * NB + eid] = cS[i];   // bucket-major: scan kernel reads coalesced
      bhD[i * NB + eid] = cD[i];
    }
  }
}

// ---- P2a: per-bucket exclusive prefix over blocks (in place); totals out.
// One wave per (sort,bucket).
__global__ __launch_bounds__(256) void scanblk_k(int* __restrict__ bhS, int* __restrict__ bhD,
                                                 int* __restrict__ tot, int NBUK, int NB) {
  int wv = (int)((blockIdx.x * 256 + threadIdx.x) >> 6);
  int lane = threadIdx.x & 63;
  if (wv >= 2 * NBUK) return;
  int* bh = (wv < NBUK) ? bhS : bhD;
  int bu = (wv < NBUK) ? wv : wv - NBUK;
  int run = 0;
  for (int c = 0; c < NB; c += 64) {
    int idx = c + lane;
    int v = (idx < NB) ? bh[bu * NB + idx] : 0;
    int xi = v;
    #pragma unroll
    for (int dd = 1; dd < 64; dd <<= 1) { int t = __shfl_up(xi, dd); if (lane >= dd) xi += t; }
    if (idx < NB) bh[bu * NB + idx] = run + xi - v;
    run += __shfl(xi, 63);
  }
  if (lane == 0) tot[wv] = run;
}

// ---- P2b: exclusive scan of bucket totals -> bucket bases (both sorts).
__global__ void bukscan_k(const int* __restrict__ tot, int* __restrict__ baseS,
                          int* __restrict__ baseD, int NBUK) {
  __shared__ int sm[16];
  for (int a = 0; a < 2; ++a) {
    int* bb = a ? baseD : baseS;
    int v = (threadIdx.x < NBUK) ? tot[a * NBUK + threadIdx.x] : 0;
    int lane = threadIdx.x & 63, wid = threadIdx.x >> 6;
    int xi = v;
    #pragma unroll
    for (int dd = 1; dd < 64; dd <<= 1) { int t = __shfl_up(xi, dd); if (lane >= dd) xi += t; }
    if (lane == 63) sm[wid] = xi;
    __syncthreads();
    if (wid == 0) {
      int s2 = (lane < 16) ? sm[lane] : 0;
      #pragma unroll
      for (int dd = 1; dd < 16; dd <<= 1) { int t = __shfl_up(s2, dd); if (lane >= dd) s2 += t; }
      if (lane < 16) sm[lane] = s2;
    }
    __syncthreads();
    int incl = xi + (wid ? sm[wid - 1] : 0);
    if (threadIdx.x < NBUK) bb[threadIdx.x] = incl - v;
    if (threadIdx.x == NBUK - 1) bb[NBUK] = incl;   // == E
    __syncthreads();
  }
}

// ---- P3: scatter into bucket-major temps. All rank atomics are LDS-scope.
__global__ __launch_bounds__(256) void bucket_scatter_k(
    const void* __restrict__ ei, const float* __restrict__ wm,
    const int* __restrict__ bhS, const int* __restrict__ bhD,
    const int* __restrict__ baseS, const int* __restrict__ baseD,
    uint2* __restrict__ tmpS, uint2* __restrict__ tmpD,
    int E, int NBUK, int NB) {
  __shared__ int rS[MAXBUK], rD[MAXBUK], cS[MAXBUK], cD[MAXBUK];
  __shared__ int s64;
  int eid = blockIdx.x;
  if (threadIdx.x == 0) s64 = detect64(ei, E);
  for (int i = threadIdx.x; i < NBUK; i += 256) {
    rS[i] = baseS[i] + bhS[i * NB + eid];
    rD[i] = baseD[i] + bhD[i * NB + eid];
    cS[i] = 0; cD[i] = 0;
  }
  __syncthreads();
  int is64 = s64;
  int base = eid * CHUNK + threadIdx.x;
  #pragma unroll
  for (int kk = 0; kk < CHUNK / 256; ++kk) {
    int e = base + kk * 256;
    if (e < E) {
      int s = ld_idx(ei, e, is64);
      int d = ld_idx(ei, (long long)e + E, is64);
      float w = wm[e];
      int bs = s >> 7, bd = d >> 7;
      int pS = rS[bs] + atomicAdd(&cS[bs], 1);
      int pD = rD[bd] + atomicAdd(&cD[bd], 1);
      tmpS[pS] = make_uint2((unsigned)(s & 127), __float_as_uint(w));
      tmpD[pD] = make_uint2((unsigned)s | ((unsigned)(d & 127) << 17), __float_as_uint(w));
    }
  }
}

// ---- P4: per-bucket counting sort -> offS/offD + csw/csde (final CSR).
__global__ __launch_bounds__(256) void bucket_rank_k(
    const uint2* __restrict__ tmpS, const uint2* __restrict__ tmpD,
    const int* __restrict__ baseS, const int* __restrict__ baseD,
    int* __restrict__ offS, int* __restrict__ offD,
    float* __restrict__ csw, uint2* __restrict__ csde, int NBUK, int N, int E) {
  int bkid = blockIdx.x;
  int isD = bkid >= NBUK;
  int bu = isD ? bkid - NBUK : bkid;
  const uint2* tmp = isD ? tmpD : tmpS;
  const int* bb = isD ? baseD : baseS;
  int start = bb[bu], end = bb[bu + 1];
  __shared__ int cnt[128];
  __shared__ int aux[2];
  if (threadIdx.x < 128) cnt[threadIdx.x] = 0;
  if (bkid == 0 && threadIdx.x == 0) { offS[N] = E; offD[N] = E; }
  __syncthreads();
  for (int i = start + threadIdx.x; i < end; i += 256) {
    unsigned key = tmp[i].x;
    int bin = isD ? (int)(key >> 17) : (int)(key & 127u);
    atomicAdd(&cnt[bin], 1);
  }
  __syncthreads();
  int lane = threadIdx.x & 63, wid = threadIdx.x >> 6;
  int v = 0, xi = 0;
  if (threadIdx.x < 128) {            // waves 0,1 fully active
    v = cnt[threadIdx.x];
    xi = v;
    #pragma unroll
    for (int dd = 1; dd < 64; dd <<= 1) { int t = __shfl_up(xi, dd); if (lane >= dd) xi += t; }
    if (lane == 63) aux[wid] = xi;
  }
  __syncthreads();
  if (threadIdx.x < 128) {
    int ex = xi - v + (wid ? aux[0] : 0);
    int node = bu * 128 + threadIdx.x;
    int* off = isD ? offD : offS;
    if (node < N) off[node] = start + ex;
    cnt[threadIdx.x] = ex;            // cursor init
  }
  __syncthreads();
  for (int i = start + threadIdx.x; i < end; i += 256) {
    uint2 t = tmp[i];
    int bin = isD ? (int)(t.x >> 17) : (int)(t.x & 127u);
    int r2 = atomicAdd(&cnt[bin], 1);
    int pos = start + r2;
    if (isD) csde[pos] = make_uint2(t.x & 0x1ffffu, t.y);
    else     csw[pos] = __uint_as_float(t.y);
  }
}

// ---- K6: q1 scale + layer-2 scale sc2, one wave per src node. (unchanged)
__global__ void node_q1_k(float* __restrict__ x1q1, const int* __restrict__ offS,
                          const float* __restrict__ csw, float* __restrict__ sc2,
                          const float* __restrict__ g, int N) {
  int wv = (int)(((long long)blockIdx.x * blockDim.x + threadIdx.x) >> 6);
  if (wv >= N) return;
  int lane = threadIdx.x & 63;
  int s = wv;
  int beg = offS[s], end = offS[s + 1];
  if (beg == end) return;  // empty segment: q1[s]/sc2[s] never read
  float wpmax = -3.0e38f, wpmin = 3.0e38f, wnmax = -3.0e38f, wnmin = 3.0e38f;
  int zf = 0;
  for (int t = beg + lane; t < end; t += 64) {
    float w = csw[t];
    if (w > 0.f)      { wpmax = fmaxf(wpmax, w); wpmin = fminf(wpmin, w); }
    else if (w < 0.f) { wnmax = fmaxf(wnmax, w); wnmin = fminf(wnmin, w); }
    else zf = 1;
  }
  #pragma unroll
  for (int d = 1; d < 64; d <<= 1) {
    wpmax = fmaxf(wpmax, __shfl_xor(wpmax, d));
    wpmin = fminf(wpmin, __shfl_xor(wpmin, d));
    wnmax = fmaxf(wnmax, __shfl_xor(wnmax, d));
    wnmin = fminf(wnmin, __shfl_xor(wnmin, d));
    zf |= __shfl_xor(zf, d);
  }
  int li = lane & 15, p = lane >> 4;
  float gp = g[lane], gn = g[64 + lane];
  float gp2 = g[128 + li], gn2 = g[144 + li];
  float m = -3.0e38f, m2 = -3.0e38f;
  if (wpmax > -1.0e38f) { m = fmaxf(m, gp > 0.f ? wpmax * gp : wpmin * gp);
                          m2 = fmaxf(m2, gp2 > 0.f ? wpmax * gp2 : wpmin * gp2); }
  if (wnmax > -1.0e38f) { m = fmaxf(m, gn > 0.f ? wnmax * gn : wnmin * gn);
                          m2 = fmaxf(m2, gn2 > 0.f ? wnmax * gn2 : wnmin * gn2); }
  if (zf) { m = fmaxf(m, 0.f); m2 = fmaxf(m2, 0.f); }
  float den = 0.f, den2p = 0.f;
  for (int t0 = beg; t0 < end; t0 += 64) {
    int nv = min(64, end - t0);
    float wl = (t0 + lane < end) ? csw[t0 + lane] : 0.f;
    for (int j = 0; j < nv; ++j) {
      float w = __shfl(wl, j);
      den += __expf(w * (w > 0.f ? gp : gn) - m);
    }
    for (int j = p; j < nv; j += 4) {
      float w = __shfl(wl, j);
      den2p += __expf(w * (w > 0.f ? gp2 : gn2) - m2);
    }
  }
  den2p += __shfl_xor(den2p, 16);
  den2p += __shfl_xor(den2p, 32);
  int o = s * 64 + lane;
  x1q1[o] = x1q1[o] * (__expf(-m) / (den + 1e-16f));
  if (lane < 16) sc2[s * 16 + li] = __expf(-m2) / (den2p + 1e-16f);
}

// ---- K7: h[d] = elu( sum_in exp(w*g)*q1[src] ), one wave per dst node. (unchanged)
__global__ void msg1_k(const float* __restrict__ q1, float* __restrict__ h,
                       const int* __restrict__ offD, const uint2* __restrict__ csde,
                       const float* __restrict__ g, int N) {
  int wv = (int)(((long long)blockIdx.x * blockDim.x + threadIdx.x) >> 6);
  if (wv >= N) return;
  int lane = threadIdx.x & 63;
  int d = wv;
  int beg = offD[d], end = offD[d + 1];
  float gp = g[lane], gn = g[64 + lane];
  float acc0 = 0.f, acc1 = 0.f;
  for (int t0 = beg; t0 < end; t0 += 64) {
    int nv = min(64, end - t0);
    uint2 ew = (t0 + lane < end) ? csde[t0 + lane] : make_uint2(0u, 0u);
    int sl = (int)ew.x;
    float wl = __uint_as_float(ew.y);
    int j = 0;
    for (; j + 1 < nv; j += 2) {
      int   sA = __shfl(sl, j);     float wA = __shfl(wl, j);
      int   sB = __shfl(sl, j + 1); float wB = __shfl(wl, j + 1);
      acc0 += __expf(wA * (wA > 0.f ? gp : gn)) * q1[sA * 64 + lane];
      acc1 += __expf(wB * (wB > 0.f ? gp : gn)) * q1[sB * 64 + lane];
    }
    if (j < nv) {
      int sA = __shfl(sl, j); float wA = __shfl(wl, j);
      acc0 += __expf(wA * (wA > 0.f ? gp : gn)) * q1[sA * 64 + lane];
    }
  }
  float acc = acc0 + acc1;
  h[d * 64 + lane] = acc > 0.f ? acc : (__expf(acc) - 1.f);
}

// ---- K5b: x2q2 = (h @ lin2_w.T + b) * sc2   (q2 directly) (unchanged)
__global__ void gemm2_k(const float* __restrict__ h, const float* __restrict__ W,
                        const float* __restrict__ b, const float* __restrict__ sc2,
                        float* __restrict__ x2, int N) {
  long long idx = (long long)blockIdx.x * blockDim.x + threadIdx.x;
  if (idx >= (long long)N * 16) return;
  int n = (int)(idx >> 4), i = (int)(idx & 15);
  const float* hr = h + (long long)n * 64;
  const float* wr = W + i * 64;
  float acc = 0.f;
  #pragma unroll
  for (int k = 0; k < 64; k += 4) {
    float4 a = *(const float4*)&hr[k];
    float4 w4 = *(const float4*)&wr[k];
    acc += a.x * w4.x + a.y * w4.y + a.z * w4.z + a.w * w4.w;
  }
  x2[idx] = (acc + b[i]) * sc2[idx];
}

// ---- K9: out2 aggregation + log_softmax fused (unchanged)
__global__ void msg2_k(const float* __restrict__ q2, float* __restrict__ out,
                       const int* __restrict__ offD, const uint2* __restrict__ csde,
                       const float* __restrict__ g, int N) {
  int wv = (int)(((long long)blockIdx.x * blockDim.x + threadIdx.x) >> 6);
  if (wv >= N) return;
  int lane = threadIdx.x & 63, i = lane & 15, p = lane >> 4;
  int d = wv;
  int beg = offD[d], end = offD[d + 1];
  float gp = g[128 + i], gn = g[144 + i];
  float accp = 0.f;
  for (int t0 = beg; t0 < end; t0 += 64) {
    int nv = min(64, end - t0);
    uint2 ew = (t0 + lane < end) ? csde[t0 + lane] : make_uint2(0u, 0u);
    int sl = (int)ew.x;
    float wl = __uint_as_float(ew.y);
    for (int j = p; j < nv; j += 4) {
      int s = __shfl(sl, j);
      float w = __shfl(wl, j);
      accp += __expf(w * (w > 0.f ? gp : gn)) * q2[s * 16 + i];
    }
  }
  float acc = accp;
  acc += __shfl_xor(acc, 16);
  acc += __shfl_xor(acc, 32);
  float mx = acc;
  #pragma unroll
  for (int d2 = 1; d2 < 16; d2 <<= 1) mx = fmaxf(mx, __shfl_xor(mx, d2));
  float se = __expf(acc - mx);
  #pragma unroll
  for (int d2 = 1; d2 < 16; d2 <<= 1) se += __shfl_xor(se, d2);
  float ls = acc - mx - __logf(se);
  if (p == 0) out[d * 16 + i] = ls;
}

extern "C" void kernel_launch(void* const* d_in, const int* in_sizes, int n_in,
                              void* d_out, int out_size, void* d_ws, size_t ws_size,
                              hipStream_t stream) {
  const float* x    = (const float*)d_in[0];
  const void*  ei   = d_in[1];
  const float* wm   = (const float*)d_in[2];
  const float* l1w  = (const float*)d_in[3];
  const float* l1b  = (const float*)d_in[4];
  const float* m1w1 = (const float*)d_in[5];
  const float* m1w2 = (const float*)d_in[6];
  const float* l2w  = (const float*)d_in[8];
  const float* l2b  = (const float*)d_in[9];
  const float* m2w1 = (const float*)d_in[10];
  const float* m2w2 = (const float*)d_in[11];
  // mlp*_b2 (d_in[7], d_in[12]) cancel in the segment softmax — unused.

  int N = in_sizes[0] / 256;
  int E = in_sizes[2];
  float* out = (float*)d_out;

  int NBUK = (N + 127) >> 7;            // node buckets of 128 (782 for N=100k)
  int EB = (E + CHUNK - 1) / CHUNK;     // edge blocks (782 for E=3.2M)
  int NB = EB;
  int GB = (N + 127) / 128;             // gemm1 tiles

  char* base = (char*)d_ws;
  size_t off = 0;
  auto alloc = [&](size_t bytes) -> char* {
    char* p = base + off;
    off = (off + bytes + 255) & ~(size_t)255;
    return p;
  };
  float* g    = (float*)alloc(1024);
  int*  bhS   = (int*)alloc((size_t)NBUK * NB * 4);
  int*  bhD   = (int*)alloc((size_t)NBUK * NB * 4);
  int*  tot   = (int*)alloc((size_t)2 * NBUK * 4);
  int*  baseS = (int*)alloc((size_t)(NBUK + 1) * 4);
  int*  baseD = (int*)alloc((size_t)(NBUK + 1) * 4);
  int*  offS  = (int*)alloc((size_t)(N + 1) * 4);
  int*  offD  = (int*)alloc((size_t)(N + 1) * 4);
  float* sc2  = (float*)alloc((size_t)N * 16 * 4);
  uint2* tmpS = (uint2*)alloc((size_t)E * 8);
  uint2* tmpD = (uint2*)alloc((size_t)E * 8);
  float* csw  = (float*)alloc((size_t)E * 4);
  uint2* csde = (uint2*)alloc((size_t)E * 8);
  float* x1q1 = (float*)alloc((size_t)N * 64 * 4);   // x1, then q1 in-place
  // tmpS/tmpD are dead after bucket_rank_k -> alias h and x2q2 onto them.
  float* h    = ((size_t)E * 8 >= (size_t)N * 256) ? (float*)tmpD
                                                   : (float*)alloc((size_t)N * 256);
  float* x2q2 = ((size_t)E * 8 >= (size_t)N * 64)  ? (float*)tmpS
                                                   : (float*)alloc((size_t)N * 64);

  gvec_k<<<1, 64, 0, stream>>>(m1w1, m1w2, m2w1, m2w2, g);

  // grid: blocks with k%5==4 are gemm tiles (k/5 < GB), others map to
  // eid = k - k/5 (bijective). grid = 5*GB covers gid in [0,GB); need
  // enough r<4 blocks for EB: k - k/5 >= EB  ->  grid >= EB + (EB+3)/4.
  int grid = 5 * GB;
  int need = EB + (EB + 3) / 4;
  if (grid < need) grid = need;
  fused_hist_gemm1_k<<<grid, 256, 0, stream>>>(ei, bhS, bhD, E, EB, NBUK, NB,
                                               x, l1w, l1b, x1q1, N, GB);

  scanblk_k<<<(2 * NBUK + 3) / 4, 256, 0, stream>>>(bhS, bhD, tot, NBUK, NB);
  bukscan_k<<<1, 1024, 0, stream>>>(tot, baseS, baseD, NBUK);
  bucket_scatter_k<<<EB, 256, 0, stream>>>(ei, wm, bhS, bhD, baseS, baseD,
                                           tmpS, tmpD, E, NBUK, NB);
  bucket_rank_k<<<2 * NBUK, 256, 0, stream>>>(tmpS, tmpD, baseS, baseD,
                                              offS, offD, csw, csde, NBUK, N, E);

  node_q1_k<<<(N + 3) / 4, 256, 0, stream>>>(x1q1, offS, csw, sc2, g, N);
  msg1_k<<<(N + 3) / 4, 256, 0, stream>>>(x1q1, h, offD, csde, g, N);
  gemm2_k<<<(N * 16 + 255) / 256, 256, 0, stream>>>(h, l2w, l2b, sc2, x2q2, N);
  msg2_k<<<(N + 3) / 4, 256, 0, stream>>>(x2q2, out, offD, csde, g, N);
}